// Round 1
// 97.719 us; speedup vs baseline: 1.0248x; 1.0248x over previous
//
#include <hip/hip_runtime.h>
#include <hip/hip_fp16.h>

typedef __attribute__((ext_vector_type(4))) float f32x4;
typedef __attribute__((ext_vector_type(8))) _Float16 f16x8;
typedef __attribute__((ext_vector_type(4))) unsigned int u32x4;

// float -> fp16 bits, round-nearest-even
__device__ __forceinline__ unsigned short f2h(float f) {
  __half h = __float2half_rn(f);
  unsigned short u;
  __builtin_memcpy(&u, &h, 2);
  return u;
}
// dword <-> __half2 helpers (ext_vector elements can't be addressed directly)
__device__ __forceinline__ __half2 h2_of(unsigned int u) {
  __half2 h;
  __builtin_memcpy(&h, &u, 4);
  return h;
}
__device__ __forceinline__ unsigned int u_of(__half2 h) {
  unsigned int u;
  __builtin_memcpy(&u, &h, 4);
  return u;
}

// ---------------------------------------------------------------------------
// Prep kernel, round 14: WEIGHTS ONLY (x-transpose now fused into deform's
// prologue — the per-XCD batch slice of x is 2 MB and L2-resident, so the
// NHWC fp16 intermediate xt was a pure HBM round trip).
// Repack weight fp32 -> fp16 MFMA A-fragments:
//   wf[((ch*8 + mt)*64 + lane)*8 + j] = fp16(W[mt*16+(lane&15)]
//                                            [cc*32 + (lane>>4)*8 + j][tap])
// ch = cc*9 + tap (layouts verified R2-R12).
// ---------------------------------------------------------------------------
__global__ __launch_bounds__(256) void prep_kernel(const float* __restrict__ w,
                                                   unsigned short* __restrict__ wf) {
  int tid = blockIdx.x * 256 + threadIdx.x;   // 0..18431
  int l  = tid & 63;
  int mt = (tid >> 6) & 7;
  int ch = tid >> 9;                          // 0..35
  int cc = ch / 9, tap = ch - cc * 9;
  int co = mt * 16 + (l & 15);
  int cb = cc * 32 + (l >> 4) * 8;
  unsigned int r[8];
#pragma unroll
  for (int j = 0; j < 8; ++j)
    r[j] = f2h(w[(co * 128 + cb + j) * 9 + tap]);
  u32x4 pk;
  pk.x = r[0] | (r[1] << 16);
  pk.y = r[2] | (r[3] << 16);
  pk.z = r[4] | (r[5] << 16);
  pk.w = r[6] | (r[7] << 16);
  *reinterpret_cast<u32x4*>(wf + (size_t)tid * 8) = pk;
}

// ---------------------------------------------------------------------------
// Main kernel, round 14: R13 + fused x staging + precomputed sample addrs.
// (1) Window rows are staged straight from x (NCHW fp32): per task one
//     (r,p,cg) -> 8 coalesced dword loads (lane = p, 256 B/wave/plane, XCD-L2
//     resident since b == XCD id), f2h convert, one ds_write_b128 at
//     p-stride 272 (bank quad 4*(p+cg)%32 -> 2-way = free). Kills the prep
//     x-pass and the xt HBM round trip.
// (2) sPA[e] packs per-sample precomputed LDS addrs: laT(18b)|aX(12b)<<18|
//     oow-flag<<31 (same for bottom row in .y). Phase 1 per pg is now a b64
//     read + one add; the old twr/tin/laT chain ran 4x redundantly (once per
//     ks-wave). Rare out-of-window fallback reads x fp32 directly (8 strided
//     dwords + f2h, exec-masked, ~1-2% of lanes).
// Everything else verified from R12/R13: (row,ks) waves, 8-row fp16 window
// stride 272, fp16 v_pk_fma interp -> mfma_f32_16x16x32_f16, software-
// pipelined tap body, pairwise 5-barrier epilogue reduce, LDS-transpose
// dwordx4 stores.
// LDS: sWin 139264 B + sPA 9216 B + sWt 9216 B = 157696 B (1 block/CU).
// ---------------------------------------------------------------------------
__global__ __launch_bounds__(512, 1) void deform_kernel(const float* __restrict__ x,
                                                        const float* __restrict__ off,
                                                        const unsigned short* __restrict__ wf,
                                                        float* __restrict__ out) {
  // window: [r][p][c] bytes, p-stride 272 (16B pad), r-stride 64*272=17408
  __shared__ __align__(16) unsigned char sWin[8 * 17408];   // 139264 B
  __shared__ int2  sPA[1152];     // [row*576 + tap*64+wo] packed T/B addrs
  __shared__ uint2 sWt[1152];     // [row*576+...] 4 fp16 wts: (tl,tr),(bl,br)

  const int tid = threadIdx.x;
  const int bid = blockIdx.x;
  const int b   = bid & 7;             // XCD-affine batch
  const int ho0 = (bid >> 3) * 2;      // first of the 2 output rows
  const int r0  = min(max(ho0 - 3, 0), 56);   // window base row

  // --- stage window rows r0..r0+7 from x (fp32 NCHW -> fp16 window) ---
  {
    const float* xb = x + ((size_t)b << 19) + ((size_t)r0 << 6);
#pragma unroll
    for (int it = 0; it < 16; ++it) {
      int idx = it * 512 + tid;        // [cg:4][r:3][p:6], 0..8191
      int p  = idx & 63;               // lane = p -> coalesced reads
      int r  = (idx >> 6) & 7;
      int cg = idx >> 9;
      const float* xp = xb + (((size_t)cg) << 15) + (r << 6) + p;
      unsigned int q[8];
#pragma unroll
      for (int j = 0; j < 8; ++j) q[j] = f2h(xp[(size_t)j << 12]);
      u32x4 pk;
      pk.x = q[0] | (q[1] << 16);
      pk.y = q[2] | (q[3] << 16);
      pk.z = q[4] | (q[5] << 16);
      pk.w = q[6] | (q[7] << 16);
      *reinterpret_cast<u32x4*>(&sWin[r * 17408 + p * 272 + cg * 16]) = pk;
    }
  }

  // --- precompute packed sampling addresses + separable folded fp16 weights -
  for (int r = tid; r < 1152; r += 512) {
    int row = (r >= 576) ? 1 : 0;
    int rr  = r - row * 576;
    int tap = rr >> 6, wo = rr & 63;
    int ho = ho0 + row;
    float dy = off[((b * 18 + 2 * tap)     * 64 + ho) * 64 + wo];
    float dx = off[((b * 18 + 2 * tap + 1) * 64 + ho) * 64 + wo];
    float py = (float)(ho + (tap / 3) - 1) + dy;
    float px = (float)(wo + (tap % 3) - 1) + dx;
    float fy = floorf(py), fx = floorf(px);
    int y0 = (int)fy, x0 = (int)fx;
    float wy = py - fy, wx = px - fx;
    float wt = (y0 >= 0 && y0 < 64) ? (1.f - wy) : 0.f;
    float wb = (y0 + 1 >= 0 && y0 + 1 < 64) ? wy : 0.f;
    int y0c = min(max(y0, 0), 63), y1c = min(max(y0 + 1, 0), 63);
    int bx; float wl, wr;
    if (x0 >= 0 && x0 <= 62)      { bx = x0; wl = 1.f - wx; wr = wx;       }
    else if (x0 == -1)            { bx = 0;  wl = wx;       wr = 0.f;      }
    else if (x0 == 63)            { bx = 62; wl = 0.f;      wr = 1.f - wx; }
    else                          { bx = 0;  wl = 0.f;      wr = 0.f;      }
    // packed addresses: laT/laB (18b) | global pos (12b) << 18 | oow << 31
    int aX = y0c * 64 + bx, aY = y1c * 64 + bx;
    int twr = y0c - r0, bwr = y1c - r0;
    int tin = ((unsigned)twr < 8u) ? 1 : 0;
    int bin = ((unsigned)bwr < 8u) ? 1 : 0;
    int laT0 = (tin ? twr : 0) * 17408 + bx * 272;
    int laB0 = (bin ? bwr : 0) * 17408 + bx * 272;
    int2 pw;
    pw.x = laT0 | (aX << 18) | (tin ? 0 : (int)0x80000000);
    pw.y = laB0 | (aY << 18) | (bin ? 0 : (int)0x80000000);
    sPA[r] = pw;
    __half2 tp = __floats2half2_rn(wt * wl, wt * wr);
    __half2 bp = __floats2half2_rn(wb * wl, wb * wr);
    uint2 ww;
    ww.x = u_of(tp);
    ww.y = u_of(bp);
    sWt[r] = ww;
  }
  __syncthreads();

  const int l   = tid & 63;
  const int w   = tid >> 6;       // wave id 0..7
  const int ks  = w & 3;          // channel slab
  const int row = w >> 2;         // output row (ho0 + row)
  const int ln  = l & 15;
  const int kg  = l >> 4;         // k-group (8 consecutive channels)
  const int koff = ks * 64 + kg * 16;   // lane's channel byte offset in record
  const int ho  = ho0 + row;

  // per-lane fp32 base for the rare out-of-window fallback: channels
  // ks*32+kg*8 .. +7, planes 4096 floats apart
  const float* xfb = x + ((size_t)b << 19) + (((size_t)(ks * 32 + kg * 8)) << 12);
  const unsigned short* wfb = wf + (size_t)l * 8;

  f32x4 acc[4][8] = {};   // [pos-group][m-tile] -> AGPRs

  for (int tap = 0; tap < 9; ++tap) {
    const int ch = ks * 9 + tap;

    // A-fragments: all 8 m-tiles (full Cout per wave)
    f16x8 A[8];
    const unsigned short* wp = wfb + (size_t)(ch * 8) * 512;
#pragma unroll
    for (int mt = 0; mt < 8; ++mt)
      A[mt] = *reinterpret_cast<const f16x8*>(wp + (size_t)mt * 512);

    // ---- phase 1: issue ALL of this tap's LDS reads (+rare fallbacks) ----
    u32x4 T0[4], T1[4], B0[4], B1[4];
    uint2 wws[4];
#pragma unroll
    for (int pg = 0; pg < 4; ++pg) {
      const int e = row * 576 + tap * 64 + pg * 16 + ln;
      const int2 pa = sPA[e];
      wws[pg] = sWt[e];

      const int laT = (pa.x & 0x3FFFF) + koff;
      __builtin_memcpy(&T0[pg], &sWin[laT],       16);
      __builtin_memcpy(&T1[pg], &sWin[laT + 272], 16);
      const int laB = (pa.y & 0x3FFFF) + koff;
      __builtin_memcpy(&B0[pg], &sWin[laB],       16);
      __builtin_memcpy(&B1[pg], &sWin[laB + 272], 16);

      if (pa.x < 0) {   // rare: top sample row outside window -> global fp32
        const int aX = (pa.x >> 18) & 4095;
        const float* p0 = xfb + aX;
        u32x4 q0, q1;
#pragma unroll
        for (int d = 0; d < 4; ++d) {
          unsigned int a0 = f2h(p0[(size_t)(2 * d)     << 12]);
          unsigned int a1 = f2h(p0[(size_t)(2 * d + 1) << 12]);
          q0[d] = a0 | (a1 << 16);
          unsigned int c0 = f2h(p0[((size_t)(2 * d)     << 12) + 1]);
          unsigned int c1 = f2h(p0[((size_t)(2 * d + 1) << 12) + 1]);
          q1[d] = c0 | (c1 << 16);
        }
        T0[pg] = q0;
        T1[pg] = q1;
      }
      if (pa.y < 0) {   // rare: bottom sample row outside window
        const int aY = (pa.y >> 18) & 4095;
        const float* p1 = xfb + aY;
        u32x4 q0, q1;
#pragma unroll
        for (int d = 0; d < 4; ++d) {
          unsigned int a0 = f2h(p1[(size_t)(2 * d)     << 12]);
          unsigned int a1 = f2h(p1[(size_t)(2 * d + 1) << 12]);
          q0[d] = a0 | (a1 << 16);
          unsigned int c0 = f2h(p1[((size_t)(2 * d)     << 12) + 1]);
          unsigned int c1 = f2h(p1[((size_t)(2 * d + 1) << 12) + 1]);
          q1[d] = c0 | (c1 << 16);
        }
        B0[pg] = q0;
        B1[pg] = q1;
      }
    }

    // ---- phase 2: interp + MFMA per pos-group ----
#pragma unroll
    for (int pg = 0; pg < 4; ++pg) {
      const uint2 ww = wws[pg];
      const __half2 wtl = __half2half2(__low2half(h2_of(ww.x)));
      const __half2 wtr = __half2half2(__high2half(h2_of(ww.x)));
      const __half2 wbl = __half2half2(__low2half(h2_of(ww.y)));
      const __half2 wbr = __half2half2(__high2half(h2_of(ww.y)));
      u32x4 pk;
#pragma unroll
      for (int d = 0; d < 4; ++d) {
        __half2 s = __hmul2(wtl, h2_of(T0[pg][d]));
        s = __hfma2(wtr, h2_of(T1[pg][d]), s);
        s = __hfma2(wbl, h2_of(B0[pg][d]), s);
        s = __hfma2(wbr, h2_of(B1[pg][d]), s);
        pk[d] = u_of(s);
      }
      f16x8 bfrag;
      __builtin_memcpy(&bfrag, &pk, 16);

#pragma unroll
      for (int mt = 0; mt < 8; ++mt)
        acc[pg][mt] = __builtin_amdgcn_mfma_f32_16x16x32_f16(A[mt], bfrag,
                                                             acc[pg][mt], 0, 0, 0);
    }
  }

  // ---- epilogue 1: pairwise LDS tree-reduce (5 barriers, parallel writes) --
  // regB at float ofs 0 (rows at row*8448), regA at 17408 (rows at +row*8448).
  // C/D layout: wo = pg*16+ln, co = mt*16 + kg*4 + reg.
  float* sF = reinterpret_cast<float*>(sWin);
#define WR_LDS(BASE)                                                           \
  { _Pragma("unroll") for (int pg = 0; pg < 4; ++pg)                           \
    _Pragma("unroll") for (int mt = 0; mt < 8; ++mt)                           \
      *reinterpret_cast<f32x4*>(&sF[(BASE) + row * 8448 + (pg * 16 + ln) * 132 + mt * 16 + kg * 4]) = acc[pg][mt]; }
#define RD_LDS(BASE)                                                           \
  { _Pragma("unroll") for (int pg = 0; pg < 4; ++pg)                           \
    _Pragma("unroll") for (int mt = 0; mt < 8; ++mt) {                         \
      f32x4 v = *reinterpret_cast<const f32x4*>(&sF[(BASE) + row * 8448 + (pg * 16 + ln) * 132 + mt * 16 + kg * 4]); \
      acc[pg][mt] += v; } }

  __syncthreads();
  if (ks == 1) WR_LDS(17408)
  if (ks == 3) WR_LDS(0)
  __syncthreads();
  if (ks == 0) RD_LDS(17408)
  if (ks == 2) RD_LDS(0)
  __syncthreads();
  if (ks == 2) WR_LDS(17408)
  __syncthreads();
  if (ks == 0) RD_LDS(17408)
#undef WR_LDS
#undef RD_LDS

  // ---- epilogue 2: transpose via LDS [co][wo] (stride 68) -> dwordx4 stores
  // transpose region at float ofs row*8704 (max 17403 < 17408 = regA base).
  {
    const int b2 = row * 8704;
    if (ks == 0) {
#pragma unroll
      for (int pg = 0; pg < 4; ++pg)
#pragma unroll
        for (int mt = 0; mt < 8; ++mt)
#pragma unroll
          for (int rg = 0; rg < 4; ++rg)
            sF[b2 + (mt * 16 + kg * 4 + rg) * 68 + pg * 16 + ln] = acc[pg][mt][rg];
    }
    __syncthreads();
    if (ks == 0) {
      const int q4  = l & 15;       // wo quad: wo = q4*4..q4*4+3
      const int ch2 = l >> 4;       // co quarter
      float* ob = out + (((size_t)b * 128) * 64 + ho) * 64 + q4 * 4;
#pragma unroll
      for (int i = 0; i < 32; ++i) {
        int co = ch2 * 32 + i;
        f32x4 v = *reinterpret_cast<const f32x4*>(&sF[b2 + co * 68 + q4 * 4]);
        *reinterpret_cast<f32x4*>(ob + (size_t)co * 4096) = v;
      }
    }
  }
}

extern "C" void kernel_launch(void* const* d_in, const int* in_sizes, int n_in,
                              void* d_out, int out_size, void* d_ws, size_t ws_size,
                              hipStream_t stream) {
  (void)in_sizes; (void)n_in; (void)out_size; (void)ws_size;
  const float* x   = (const float*)d_in[0];
  const float* off = (const float*)d_in[1];
  const float* w   = (const float*)d_in[2];
  float* out = (float*)d_out;
  unsigned short* wf = (unsigned short*)d_ws;   // 294912 B

  prep_kernel<<<72, 256, 0, stream>>>(w, wf);
  deform_kernel<<<256, 512, 0, stream>>>(x, off, wf, out);
}

// Round 2
// 96.491 us; speedup vs baseline: 1.0379x; 1.0127x over previous
//
#include <hip/hip_runtime.h>
#include <hip/hip_fp16.h>

typedef __attribute__((ext_vector_type(4))) float f32x4;
typedef __attribute__((ext_vector_type(8))) _Float16 f16x8;
typedef __attribute__((ext_vector_type(4))) unsigned int u32x4;

// float -> fp16 bits, round-nearest-even
__device__ __forceinline__ unsigned short f2h(float f) {
  __half h = __float2half_rn(f);
  unsigned short u;
  __builtin_memcpy(&u, &h, 2);
  return u;
}
// dword <-> __half2 helpers (ext_vector elements can't be addressed directly)
__device__ __forceinline__ __half2 h2_of(unsigned int u) {
  __half2 h;
  __builtin_memcpy(&h, &u, 4);
  return h;
}
__device__ __forceinline__ unsigned int u_of(__half2 h) {
  unsigned int u;
  __builtin_memcpy(&u, &h, 4);
  return u;
}

// ---------------------------------------------------------------------------
// Prep kernel (weights only, verified R14).
// Repack weight fp32 -> fp16 MFMA A-fragments:
//   wf[((ch*8 + mt)*64 + lane)*8 + j] = fp16(W[mt*16+(lane&15)]
//                                            [cc*32 + (lane>>4)*8 + j][tap])
// ch = cc*9 + tap (layouts verified R2-R12).
// ---------------------------------------------------------------------------
__global__ __launch_bounds__(256) void prep_kernel(const float* __restrict__ w,
                                                   unsigned short* __restrict__ wf) {
  int tid = blockIdx.x * 256 + threadIdx.x;   // 0..18431
  int l  = tid & 63;
  int mt = (tid >> 6) & 7;
  int ch = tid >> 9;                          // 0..35
  int cc = ch / 9, tap = ch - cc * 9;
  int co = mt * 16 + (l & 15);
  int cb = cc * 32 + (l >> 4) * 8;
  unsigned int r[8];
#pragma unroll
  for (int j = 0; j < 8; ++j)
    r[j] = f2h(w[(co * 128 + cb + j) * 9 + tap]);
  u32x4 pk;
  pk.x = r[0] | (r[1] << 16);
  pk.y = r[2] | (r[3] << 16);
  pk.z = r[4] | (r[5] << 16);
  pk.w = r[6] | (r[7] << 16);
  *reinterpret_cast<u32x4*>(wf + (size_t)tid * 8) = pk;
}

// ---------------------------------------------------------------------------
// Main kernel, round 15: R14 + dependent-chain pipelining.
// (1) sTab[e] = int4 {packed laT|aX|oow, packed laB|aY|oow, top-wts, bot-wts}
//     -> ONE ds_read_b128 per (pg,tap) replaces b64 pair (sPA+sWt).
// (2) Table reads double-buffered across taps: tap t+1's 4 entries prefetched
//     during tap t's body, so each tap's T/B window reads issue immediately
//     from registers (removes the leading ~120-cyc LDS latency of the
//     table->address->read chain; at 2 waves/SIMD that latency was exposed).
// (3) Rolling 3-slot T/B register window (issue pg0-2 / consume pg0 / issue
//     pg3 / consume pg1-3) frees 16 VGPRs to pay for (2) and keeps the
//     kernel under the 256-VGPR 8-waves/CU cliff.
// Everything else verified R12-R14: fused fp32->fp16 window staging (XCD-L2
// resident, b == XCD id), 8-row window p-stride 272, fp16 v_pk_fma interp ->
// mfma_f32_16x16x32_f16, pairwise 5-barrier epilogue reduce, LDS-transpose
// dwordx4 stores.
// LDS: sWin 139264 B + sTab 18432 B = 157696 B (1 block/CU, 8 waves).
// ---------------------------------------------------------------------------
__global__ __launch_bounds__(512, 1) void deform_kernel(const float* __restrict__ x,
                                                        const float* __restrict__ off,
                                                        const unsigned short* __restrict__ wf,
                                                        float* __restrict__ out) {
  // window: [r][p][c] bytes, p-stride 272 (16B pad), r-stride 64*272=17408
  __shared__ __align__(16) unsigned char sWin[8 * 17408];   // 139264 B
  __shared__ int4 sTab[1152];   // [row*576 + tap*64 + wo] addrs + fp16 wts

  const int tid = threadIdx.x;
  const int bid = blockIdx.x;
  const int b   = bid & 7;             // XCD-affine batch
  const int ho0 = (bid >> 3) * 2;      // first of the 2 output rows
  const int r0  = min(max(ho0 - 3, 0), 56);   // window base row

  // --- stage window rows r0..r0+7 from x (fp32 NCHW -> fp16 window) ---
  {
    const float* xb = x + ((size_t)b << 19) + ((size_t)r0 << 6);
#pragma unroll
    for (int it = 0; it < 16; ++it) {
      int idx = it * 512 + tid;        // [cg:4][r:3][p:6], 0..8191
      int p  = idx & 63;               // lane = p -> coalesced reads
      int r  = (idx >> 6) & 7;
      int cg = idx >> 9;
      const float* xp = xb + (((size_t)cg) << 15) + (r << 6) + p;
      unsigned int q[8];
#pragma unroll
      for (int j = 0; j < 8; ++j) q[j] = f2h(xp[(size_t)j << 12]);
      u32x4 pk;
      pk.x = q[0] | (q[1] << 16);
      pk.y = q[2] | (q[3] << 16);
      pk.z = q[4] | (q[5] << 16);
      pk.w = q[6] | (q[7] << 16);
      *reinterpret_cast<u32x4*>(&sWin[r * 17408 + p * 272 + cg * 16]) = pk;
    }
  }

  // --- precompute packed sampling addresses + separable folded fp16 weights -
  for (int r = tid; r < 1152; r += 512) {
    int row = (r >= 576) ? 1 : 0;
    int rr  = r - row * 576;
    int tap = rr >> 6, wo = rr & 63;
    int ho = ho0 + row;
    float dy = off[((b * 18 + 2 * tap)     * 64 + ho) * 64 + wo];
    float dx = off[((b * 18 + 2 * tap + 1) * 64 + ho) * 64 + wo];
    float py = (float)(ho + (tap / 3) - 1) + dy;
    float px = (float)(wo + (tap % 3) - 1) + dx;
    float fy = floorf(py), fx = floorf(px);
    int y0 = (int)fy, x0 = (int)fx;
    float wy = py - fy, wx = px - fx;
    float wt = (y0 >= 0 && y0 < 64) ? (1.f - wy) : 0.f;
    float wb = (y0 + 1 >= 0 && y0 + 1 < 64) ? wy : 0.f;
    int y0c = min(max(y0, 0), 63), y1c = min(max(y0 + 1, 0), 63);
    int bx; float wl, wr;
    if (x0 >= 0 && x0 <= 62)      { bx = x0; wl = 1.f - wx; wr = wx;       }
    else if (x0 == -1)            { bx = 0;  wl = wx;       wr = 0.f;      }
    else if (x0 == 63)            { bx = 62; wl = 0.f;      wr = 1.f - wx; }
    else                          { bx = 0;  wl = 0.f;      wr = 0.f;      }
    // packed addresses: laT/laB (18b) | global pos (12b) << 18 | oow << 31
    int aX = y0c * 64 + bx, aY = y1c * 64 + bx;
    int twr = y0c - r0, bwr = y1c - r0;
    int tin = ((unsigned)twr < 8u) ? 1 : 0;
    int bin = ((unsigned)bwr < 8u) ? 1 : 0;
    int laT0 = (tin ? twr : 0) * 17408 + bx * 272;
    int laB0 = (bin ? bwr : 0) * 17408 + bx * 272;
    int4 pw;
    pw.x = laT0 | (aX << 18) | (tin ? 0 : (int)0x80000000);
    pw.y = laB0 | (aY << 18) | (bin ? 0 : (int)0x80000000);
    pw.z = (int)u_of(__floats2half2_rn(wt * wl, wt * wr));
    pw.w = (int)u_of(__floats2half2_rn(wb * wl, wb * wr));
    sTab[r] = pw;
  }
  __syncthreads();

  const int l   = tid & 63;
  const int w   = tid >> 6;       // wave id 0..7
  const int ks  = w & 3;          // channel slab
  const int row = w >> 2;         // output row (ho0 + row)
  const int ln  = l & 15;
  const int kg  = l >> 4;         // k-group (8 consecutive channels)
  const int koff = ks * 64 + kg * 16;   // lane's channel byte offset in record
  const int ho  = ho0 + row;
  const int tbase = row * 576 + ln;

  // per-lane fp32 base for the rare out-of-window fallback: channels
  // ks*32+kg*8 .. +7, planes 4096 floats apart
  const float* xfb = x + ((size_t)b << 19) + (((size_t)(ks * 32 + kg * 8)) << 12);
  const unsigned short* wfb = wf + (size_t)l * 8;

  f32x4 acc[4][8] = {};   // [pos-group][m-tile] -> AGPRs

  // preload tap 0's table entries
  int4 tbc[4];
#pragma unroll
  for (int pg = 0; pg < 4; ++pg) tbc[pg] = sTab[tbase + pg * 16];

#define ISSUE(S, PG) {                                                         \
    const int4 tb = tbc[PG];                                                   \
    const int laT = (tb.x & 0x3FFFF) + koff;                                   \
    __builtin_memcpy(&T0[S], &sWin[laT],       16);                            \
    __builtin_memcpy(&T1[S], &sWin[laT + 272], 16);                            \
    const int laB = (tb.y & 0x3FFFF) + koff;                                   \
    __builtin_memcpy(&B0[S], &sWin[laB],       16);                            \
    __builtin_memcpy(&B1[S], &sWin[laB + 272], 16);                            \
    if (tb.x < 0) {   /* rare: top sample row outside window -> global fp32 */ \
      const float* p0 = xfb + ((tb.x >> 18) & 4095);                           \
      u32x4 q0, q1;                                                            \
      _Pragma("unroll") for (int d = 0; d < 4; ++d) {                          \
        unsigned int a0 = f2h(p0[(size_t)(2 * d)     << 12]);                  \
        unsigned int a1 = f2h(p0[(size_t)(2 * d + 1) << 12]);                  \
        q0[d] = a0 | (a1 << 16);                                               \
        unsigned int c0 = f2h(p0[((size_t)(2 * d)     << 12) + 1]);            \
        unsigned int c1 = f2h(p0[((size_t)(2 * d + 1) << 12) + 1]);            \
        q1[d] = c0 | (c1 << 16);                                               \
      }                                                                        \
      T0[S] = q0; T1[S] = q1;                                                  \
    }                                                                          \
    if (tb.y < 0) {   /* rare: bottom sample row outside window */             \
      const float* p1 = xfb + ((tb.y >> 18) & 4095);                           \
      u32x4 q0, q1;                                                            \
      _Pragma("unroll") for (int d = 0; d < 4; ++d) {                          \
        unsigned int a0 = f2h(p1[(size_t)(2 * d)     << 12]);                  \
        unsigned int a1 = f2h(p1[(size_t)(2 * d + 1) << 12]);                  \
        q0[d] = a0 | (a1 << 16);                                               \
        unsigned int c0 = f2h(p1[((size_t)(2 * d)     << 12) + 1]);            \
        unsigned int c1 = f2h(p1[((size_t)(2 * d + 1) << 12) + 1]);            \
        q1[d] = c0 | (c1 << 16);                                               \
      }                                                                        \
      B0[S] = q0; B1[S] = q1;                                                  \
    }                                                                          \
  }

#define INTERP(S, PG) {                                                        \
    const __half2 wtl = __half2half2(__low2half(h2_of((unsigned)tbc[PG].z)));  \
    const __half2 wtr = __half2half2(__high2half(h2_of((unsigned)tbc[PG].z))); \
    const __half2 wbl = __half2half2(__low2half(h2_of((unsigned)tbc[PG].w)));  \
    const __half2 wbr = __half2half2(__high2half(h2_of((unsigned)tbc[PG].w))); \
    u32x4 pk;                                                                  \
    _Pragma("unroll") for (int d = 0; d < 4; ++d) {                            \
      __half2 s = __hmul2(wtl, h2_of(T0[S][d]));                               \
      s = __hfma2(wtr, h2_of(T1[S][d]), s);                                    \
      s = __hfma2(wbl, h2_of(B0[S][d]), s);                                    \
      s = __hfma2(wbr, h2_of(B1[S][d]), s);                                    \
      pk[d] = u_of(s);                                                         \
    }                                                                          \
    f16x8 bfrag;                                                               \
    __builtin_memcpy(&bfrag, &pk, 16);                                         \
    _Pragma("unroll") for (int mt = 0; mt < 8; ++mt)                           \
      acc[PG][mt] = __builtin_amdgcn_mfma_f32_16x16x32_f16(A[mt], bfrag,       \
                                                           acc[PG][mt], 0, 0, 0); \
  }

  for (int tap = 0; tap < 9; ++tap) {
    // prefetch next tap's table entries (hidden under this tap's body)
    int4 tbn[4];
    if (tap < 8) {
#pragma unroll
      for (int pg = 0; pg < 4; ++pg)
        tbn[pg] = sTab[tbase + (tap + 1) * 64 + pg * 16];
    }

    // A-fragments: all 8 m-tiles (full Cout per wave), global L2-hot
    f16x8 A[8];
    const unsigned short* wp = wfb + (size_t)((ks * 9 + tap) * 8) * 512;
#pragma unroll
    for (int mt = 0; mt < 8; ++mt)
      A[mt] = *reinterpret_cast<const f16x8*>(wp + (size_t)mt * 512);

    // rolling 3-slot T/B window: addresses come straight from tbc registers
    u32x4 T0[3], T1[3], B0[3], B1[3];
    ISSUE(0, 0)
    ISSUE(1, 1)
    ISSUE(2, 2)
    INTERP(0, 0)
    ISSUE(0, 3)
    INTERP(1, 1)
    INTERP(2, 2)
    INTERP(0, 3)

#pragma unroll
    for (int pg = 0; pg < 4; ++pg) tbc[pg] = tbn[pg];
  }
#undef ISSUE
#undef INTERP

  // ---- epilogue 1: pairwise LDS tree-reduce (5 barriers, parallel writes) --
  // regB at float ofs 0 (rows at row*8448), regA at 17408 (rows at +row*8448).
  // C/D layout: wo = pg*16+ln, co = mt*16 + kg*4 + reg.
  float* sF = reinterpret_cast<float*>(sWin);
#define WR_LDS(BASE)                                                           \
  { _Pragma("unroll") for (int pg = 0; pg < 4; ++pg)                           \
    _Pragma("unroll") for (int mt = 0; mt < 8; ++mt)                           \
      *reinterpret_cast<f32x4*>(&sF[(BASE) + row * 8448 + (pg * 16 + ln) * 132 + mt * 16 + kg * 4]) = acc[pg][mt]; }
#define RD_LDS(BASE)                                                           \
  { _Pragma("unroll") for (int pg = 0; pg < 4; ++pg)                           \
    _Pragma("unroll") for (int mt = 0; mt < 8; ++mt) {                         \
      f32x4 v = *reinterpret_cast<const f32x4*>(&sF[(BASE) + row * 8448 + (pg * 16 + ln) * 132 + mt * 16 + kg * 4]); \
      acc[pg][mt] += v; } }

  __syncthreads();
  if (ks == 1) WR_LDS(17408)
  if (ks == 3) WR_LDS(0)
  __syncthreads();
  if (ks == 0) RD_LDS(17408)
  if (ks == 2) RD_LDS(0)
  __syncthreads();
  if (ks == 2) WR_LDS(17408)
  __syncthreads();
  if (ks == 0) RD_LDS(17408)
#undef WR_LDS
#undef RD_LDS

  // ---- epilogue 2: transpose via LDS [co][wo] (stride 68) -> dwordx4 stores
  // transpose region at float ofs row*8704 (max 17403 < 17408 = regA base).
  {
    const int b2 = row * 8704;
    if (ks == 0) {
#pragma unroll
      for (int pg = 0; pg < 4; ++pg)
#pragma unroll
        for (int mt = 0; mt < 8; ++mt)
#pragma unroll
          for (int rg = 0; rg < 4; ++rg)
            sF[b2 + (mt * 16 + kg * 4 + rg) * 68 + pg * 16 + ln] = acc[pg][mt][rg];
    }
    __syncthreads();
    if (ks == 0) {
      const int q4  = l & 15;       // wo quad: wo = q4*4..q4*4+3
      const int ch2 = l >> 4;       // co quarter
      float* ob = out + (((size_t)b * 128) * 64 + ho) * 64 + q4 * 4;
#pragma unroll
      for (int i = 0; i < 32; ++i) {
        int co = ch2 * 32 + i;
        f32x4 v = *reinterpret_cast<const f32x4*>(&sF[b2 + co * 68 + q4 * 4]);
        *reinterpret_cast<f32x4*>(ob + (size_t)co * 4096) = v;
      }
    }
  }
}

extern "C" void kernel_launch(void* const* d_in, const int* in_sizes, int n_in,
                              void* d_out, int out_size, void* d_ws, size_t ws_size,
                              hipStream_t stream) {
  (void)in_sizes; (void)n_in; (void)out_size; (void)ws_size;
  const float* x   = (const float*)d_in[0];
  const float* off = (const float*)d_in[1];
  const float* w   = (const float*)d_in[2];
  float* out = (float*)d_out;
  unsigned short* wf = (unsigned short*)d_ws;   // 294912 B

  prep_kernel<<<72, 256, 0, stream>>>(w, wf);
  deform_kernel<<<256, 512, 0, stream>>>(x, off, wf, out);
}